// Round 13
// baseline (957.480 us; speedup 1.0000x reference)
//
#include <hip/hip_runtime.h>
#include <hip/hip_bf16.h>

// B=64 graphs, N=512 pts, F0=6, K=8, conv out C=256, hidden H=336,
// m1 in 1030 (pad->1056), head 256->128->3.  fp32 in/out.
// R14: xj-factorization (Pa=x@W1a+b1, Pb=x@W1b; conv gathers, no GEMM1).
// R19: layer 1 point-factored. R20: knn Q-hoist; pool fused into MODE2.
// R24: norms fused into xbprep; 950.7us (BEST).
// R25: conv barrier diet 5->2: (a) knn indices read per-thread (L1
// broadcast) — no rowi/rowj LDS stage/barrier; (b) zero-pad folded into
// h1 build; (c) epilogue stages into disjoint shq[4][512] (no alias with
// h1 -> no barrier between GEMM2 and epilogue). LDS 23.5->27.3KB (still
// 4 blocks/CU). Layer-4 conv: xfl/nrm outputs are DEAD (m1 reads xcat
// only) -> nullptr, -33.5MB stores.

#define DEVFN __device__ __forceinline__
DEVFN float lrelu(float v) { return fmaxf(v, 0.01f * v); }

using bf16x8 = __attribute__((ext_vector_type(8))) short;
using f32x4  = __attribute__((ext_vector_type(4))) float;

template<int N> struct IC { static constexpr int value = N; };

DEVFN unsigned short f2bf(float v) {
    __hip_bfloat16 h = __float2bfloat16(v);
    return *(unsigned short*)&h;
}
DEVFN float bf2f(unsigned short u) {
    return __uint_as_float((unsigned)u << 16);
}

// ---------------------------------------------------------------------------
// weight packing: fp32 [K][N] -> bf16 B-fragment layout [kt][nt][lane][8]
// ---------------------------------------------------------------------------
struct PDesc { const float* src; unsigned short* dst; int Kt, NT, N, mode, p0, p1, Ksrc; };
struct PTable { PDesc d[13]; };

__global__ __launch_bounds__(256) void pack_kernel(PTable tb) {
    PDesc d = tb.d[blockIdx.y];
    int i = blockIdx.x * 256 + threadIdx.x;
    int tot = d.Kt * d.NT * 512;
    if (i >= tot) return;
    int j = i & 7, lane = (i >> 3) & 63;
    int tile = i >> 9;
    int nt = tile % d.NT, kt = tile / d.NT;
    int k = kt * 32 + ((lane >> 4) << 3) + j;
    int n = nt * 16 + (lane & 15);
    float v = 0.f;
    if (d.mode == 0) {
        if (k < d.Ksrc) v = d.src[(size_t)k * d.N + n];
    } else if (d.mode == 1) {
        if (k < d.p1) v = d.src[(size_t)k * d.N + n] - d.src[(size_t)(k + d.p1) * d.N + n];
        else if (k >= d.p0 && k < d.p0 + d.p1) v = d.src[(size_t)(k - d.p0 + d.p1) * d.N + n];
    } else if (d.mode == 2) {
        if (k < 6) v = d.src[(size_t)k * d.N + n];
        else if (k >= 32 && k < 1056) v = d.src[(size_t)(k - 26) * d.N + n];
    } else {
        v = d.src[(size_t)(k + d.p0) * d.N + n];
    }
    d.dst[i] = f2bf(v);
}

// ---------------------------------------------------------------------------
// xbprep: bf16 xb into xcat slice 0, zero pooled output, layer-1 norms.
// ---------------------------------------------------------------------------
__global__ __launch_bounds__(256) void xbprep_kernel(const float* __restrict__ xb,
                                                     unsigned short* __restrict__ xcat,
                                                     float* __restrict__ g,
                                                     float* __restrict__ nrm) {
    int p = blockIdx.x * 256 + threadIdx.x;
    if (p >= 32768) return;
    if (p < 16384) g[p] = 0.f;      // zero pooled output (MODE2 atomicAdds)
    unsigned short r[16];
    float s = 0.f;
    #pragma unroll
    for (int c = 0; c < 6; ++c) {
        float v = xb[p * 6 + c];
        s += v * v;
        r[c] = f2bf(v);
    }
    nrm[p] = s;
    #pragma unroll
    for (int c = 6; c < 16; ++c) r[c] = 0;
    unsigned short* xc = xcat + (size_t)p * 1056;
    #pragma unroll
    for (int c = 0; c < 16; ++c) xc[c] = r[c];
    #pragma unroll
    for (int c = 16; c < 32; ++c) xc[c] = 0;
}

// ---------------------------------------------------------------------------
// kNN fp32 (layer 1, F=6): 32 queries/block, stable top-8
// ---------------------------------------------------------------------------
template<int F>
__global__ __launch_bounds__(256) void knn_kernel(const float* __restrict__ feat,
                                                  const float* __restrict__ nrm,
                                                  int* __restrict__ knn) {
    constexpr int FP = (F == 6) ? 8 : (F + 4);
    __shared__ float Xq[32 * FP];
    __shared__ float Xc[32 * FP];
    __shared__ float qn[32], cn[32];
    __shared__ float dt[32 * 33];
    const int t  = threadIdx.x;
    const int b  = blockIdx.x >> 4;
    const int n0 = (blockIdx.x & 15) << 5;
    const float* fg = feat + (size_t)b * 512 * F;

    for (int i = t; i < 32 * F; i += 256) {
        int r = i / F, c = i - r * F;
        Xq[r * FP + c] = fg[(size_t)(n0 + r) * F + c];
    }
    if (t < 32) qn[t] = nrm[b * 512 + n0 + t];

    float d8[8]; int i8[8];
    #pragma unroll
    for (int k = 0; k < 8; ++k) { d8[k] = 3.4e38f; i8[k] = 0; }

    const int q = t >> 3, cs = t & 7;

    for (int ct = 0; ct < 16; ++ct) {
        const int c0 = ct << 5;
        __syncthreads();
        for (int i = t; i < 32 * F; i += 256) {
            int r = i / F, c = i - r * F;
            Xc[r * FP + c] = fg[(size_t)(c0 + r) * F + c];
        }
        if (t < 32) cn[t] = nrm[b * 512 + c0 + t];
        __syncthreads();

        float acc[4] = {0.f, 0.f, 0.f, 0.f};
        #pragma unroll
        for (int f = 0; f < F; ++f) {
            float qv = Xq[q * FP + f];
            #pragma unroll
            for (int j = 0; j < 4; ++j) acc[j] += qv * Xc[(cs + 8 * j) * FP + f];
        }
        #pragma unroll
        for (int j = 0; j < 4; ++j)
            dt[q * 33 + cs + 8 * j] = qn[q] + cn[cs + 8 * j] - 2.f * acc[j];
        __syncthreads();

        if (t < 32) {
            #pragma unroll 1
            for (int i = 0; i < 32; ++i) {
                float d = dt[t * 33 + i];
                if (d < d8[7]) {
                    d8[7] = d; i8[7] = c0 + i;
                    #pragma unroll
                    for (int s = 7; s >= 1; --s) {
                        if (d8[s] < d8[s - 1]) {
                            float td = d8[s]; d8[s] = d8[s - 1]; d8[s - 1] = td;
                            int   ti = i8[s]; i8[s] = i8[s - 1]; i8[s - 1] = ti;
                        }
                    }
                }
            }
        }
    }
    if (t < 32) {
        #pragma unroll
        for (int k = 0; k < 8; ++k)
            knn[((size_t)b * 512 + n0 + t) * 8 + k] = i8[k];
    }
}

// ---------------------------------------------------------------------------
// kNN via MFMA Gram (bf16x3), layers 2-4. Reads xfl (hi|lo, stride 512).
// R20: Q fragments live in 64 VGPR; only C tiles are LDS-staged.
// ---------------------------------------------------------------------------
__global__ __launch_bounds__(256, 2)
void knn_mfma(const unsigned short* __restrict__ xfl,
              const float* __restrict__ nrm,
              int* __restrict__ knn) {
    __shared__ unsigned short Ch[64 * 72], Cl[64 * 72];
    __shared__ float dt[64 * 66];
    __shared__ float qn[64], cn[64];
    float* mD = dt;
    int*   mI = (int*)(dt + 2048);

    const int t  = threadIdx.x;
    const int l  = t & 63, w = t >> 6;
    const int m16 = l & 15, q4 = l >> 4;
    const int bx = blockIdx.x;
    const int slot = bx >> 3;
    const int b  = (bx & 7) + 8 * (slot >> 3);   // graph: all its blocks on one XCD
    const int qs = (slot & 7) << 6;

    if (t < 64) qn[t] = nrm[b * 512 + qs + t];

    // Q fragments in registers: this lane's row (qs + w*16 + m16), all 512 k.
    bf16x8 qh[4][2], ql[4][2];
    {
        const unsigned short* qr = xfl + (size_t)(b * 512 + qs + w * 16 + m16) * 512;
        #pragma unroll
        for (int kc = 0; kc < 4; ++kc)
            #pragma unroll
            for (int kt = 0; kt < 2; ++kt) {
                qh[kc][kt] = *(const bf16x8*)(qr + kc * 64 + kt * 32 + q4 * 8);
                ql[kc][kt] = *(const bf16x8*)(qr + 256 + kc * 64 + kt * 32 + q4 * 8);
            }
    }

    float d8[8]; int i8[8];
    #pragma unroll
    for (int k = 0; k < 8; ++k) { d8[k] = 3.4e38f; i8[k] = 0x7fffffff; }

    const int sr = t >> 2;
    const int sc = (t & 3) << 4;
    const int tq = t & 63, sub = t >> 6;

    for (int cs = 0; cs < 8; ++cs) {
        const int c0 = cs << 6;
        if (t < 64) cn[t] = nrm[b * 512 + c0 + t];

        f32x4 acc[4];
        #pragma unroll
        for (int i = 0; i < 4; ++i) acc[i] = (f32x4){0.f, 0.f, 0.f, 0.f};

        #pragma unroll
        for (int kc = 0; kc < 4; ++kc) {
            const int k0 = kc << 6;
            __syncthreads();
            {
                const unsigned short* cr = xfl + (size_t)(b * 512 + c0 + sr) * 512;
                *(uint4*)&Ch[sr * 72 + sc]     = *(const uint4*)(cr + k0 + sc);
                *(uint4*)&Ch[sr * 72 + sc + 8] = *(const uint4*)(cr + k0 + sc + 8);
                *(uint4*)&Cl[sr * 72 + sc]     = *(const uint4*)(cr + 256 + k0 + sc);
                *(uint4*)&Cl[sr * 72 + sc + 8] = *(const uint4*)(cr + 256 + k0 + sc + 8);
            }
            __syncthreads();

            #pragma unroll
            for (int kt = 0; kt < 2; ++kt) {
                const int ko = kt * 32 + q4 * 8;
                bf16x8 ah = qh[kc][kt];
                bf16x8 al = ql[kc][kt];
                #pragma unroll
                for (int nt = 0; nt < 4; ++nt) {
                    bf16x8 bh = *(const bf16x8*)&Ch[(nt * 16 + m16) * 72 + ko];
                    bf16x8 bl = *(const bf16x8*)&Cl[(nt * 16 + m16) * 72 + ko];
                    acc[nt] = __builtin_amdgcn_mfma_f32_16x16x32_bf16(ah, bh, acc[nt], 0, 0, 0);
                    acc[nt] = __builtin_amdgcn_mfma_f32_16x16x32_bf16(ah, bl, acc[nt], 0, 0, 0);
                    acc[nt] = __builtin_amdgcn_mfma_f32_16x16x32_bf16(al, bh, acc[nt], 0, 0, 0);
                }
            }
        }

        #pragma unroll
        for (int nt = 0; nt < 4; ++nt) {
            float cv = cn[nt * 16 + m16];
            #pragma unroll
            for (int rr = 0; rr < 4; ++rr) {
                int qr = w * 16 + q4 * 4 + rr;
                dt[qr * 66 + nt * 16 + m16] = qn[qr] + cv - 2.f * acc[nt][rr];
            }
        }
        __syncthreads();

        {
            const float* drow = &dt[tq * 66 + sub * 16];
            #pragma unroll 1
            for (int j = 0; j < 16; ++j) {
                float d = drow[j];
                if (d < d8[7]) {
                    d8[7] = d; i8[7] = c0 + sub * 16 + j;
                    #pragma unroll
                    for (int s = 7; s >= 1; --s) {
                        if (d8[s] < d8[s - 1]) {
                            float td = d8[s]; d8[s] = d8[s - 1]; d8[s - 1] = td;
                            int   ti = i8[s]; i8[s] = i8[s - 1]; i8[s - 1] = ti;
                        }
                    }
                }
            }
        }
        __syncthreads();
    }

    #pragma unroll
    for (int k = 0; k < 8; ++k) {
        mD[(tq * 4 + sub) * 8 + k] = d8[k];
        mI[(tq * 4 + sub) * 8 + k] = i8[k];
    }
    __syncthreads();
    if (t < 64) {
        int p[4] = {0, 0, 0, 0};
        int outb = (b * 512 + qs + t) * 8;
        #pragma unroll 1
        for (int k = 0; k < 8; ++k) {
            float bd = 3.5e38f; int bi = 0x7fffffff; int bs = 0;
            #pragma unroll
            for (int s = 0; s < 4; ++s) {
                if (p[s] < 8) {
                    float dd = mD[(t * 4 + s) * 8 + p[s]];
                    int   ii = mI[(t * 4 + s) * 8 + p[s]];
                    if (dd < bd || (dd == bd && ii < bi)) { bd = dd; bi = ii; bs = s; }
                }
            }
            knn[outb + k] = bi;
            p[bs]++;
        }
    }
}

// ---------------------------------------------------------------------------
// R19: layer-1 point factorization (VALU, fp32 in -> bf16 P rows).
// ---------------------------------------------------------------------------
__global__ __launch_bounds__(256)
void pgemm1_kernel(const float* __restrict__ xb,
                   const float* __restrict__ W1,
                   const float* __restrict__ B1,
                   unsigned short* __restrict__ Pa,
                   unsigned short* __restrict__ Pb) {
    int i = blockIdx.x * 256 + threadIdx.x;
    if (i >= 32768 * 42) return;
    int p = i / 42, c8 = i - p * 42;
    int c0 = c8 * 8;
    float x[6];
    #pragma unroll
    for (int k = 0; k < 6; ++k) x[k] = xb[p * 6 + k];
    float sa[8], sb[8];
    #pragma unroll
    for (int j = 0; j < 8; ++j) { sa[j] = B1[c0 + j]; sb[j] = 0.f; }
    #pragma unroll
    for (int k = 0; k < 6; ++k) {
        const float* wra = W1 + (size_t)k * 336 + c0;
        const float* wrb = W1 + (size_t)(k + 6) * 336 + c0;
        #pragma unroll
        for (int j = 0; j < 8; ++j) {
            float wb = wrb[j];
            sa[j] += x[k] * (wra[j] - wb);
            sb[j] += x[k] * wb;
        }
    }
    unsigned short oa[8], ob[8];
    #pragma unroll
    for (int j = 0; j < 8; ++j) { oa[j] = f2bf(sa[j]); ob[j] = f2bf(sb[j]); }
    *(uint4*)&Pa[(size_t)p * 336 + c0] = *(uint4*)oa;
    *(uint4*)&Pb[(size_t)p * 336 + c0] = *(uint4*)ob;
}

// ---------------------------------------------------------------------------
// Point-GEMM dual: Pa = x_hi @ W1a + b1 (bias folded) and Pb = x_hi @ W1b
// (32768 x 336, K=256), 64 points/block.  (256,3).
// ---------------------------------------------------------------------------
__global__ __launch_bounds__(256, 3)
void pgemm_kernel(const unsigned short* __restrict__ xfl,
                  const unsigned short* __restrict__ Wa,
                  const unsigned short* __restrict__ Wb,
                  const float* __restrict__ B1,
                  unsigned short* __restrict__ Pa,
                  unsigned short* __restrict__ Pb) {
    __shared__ unsigned short smem[64 * 344];   // A-chunk (stride 264) / P-stage (stride 344)
    const int t = threadIdx.x;
    const int l = t & 63, w = t >> 6;
    const int q4 = l >> 4, m16 = l & 15;
    const int s1 = w * 6;
    const int bx = blockIdx.x & 511;
    const bool isA = !(blockIdx.x & 512);
    const unsigned short* W1ap = isA ? Wa : Wb;
    unsigned short*       Pp   = isA ? Pa : Pb;
    const int slot = bx >> 3;
    const int r0 = ((bx & 7) + 8 * (slot >> 3)) * 512 + (slot & 7) * 64;

    {
        const int r = t >> 2;
        const unsigned short* srow = xfl + (size_t)(r0 + r) * 512;
        #pragma unroll
        for (int s = 0; s < 8; ++s) {
            int c16 = (t & 3) + (s << 2);
            *(uint4*)&smem[r * 264 + c16 * 8] = *(const uint4*)(srow + c16 * 8);
        }
    }
    __syncthreads();

    f32x4 acc[4][6];
    #pragma unroll
    for (int mt = 0; mt < 4; ++mt)
        #pragma unroll
        for (int n = 0; n < 6; ++n) acc[mt][n] = (f32x4){0.f, 0.f, 0.f, 0.f};

    auto run = [&](auto c1c) {
        constexpr int C1 = decltype(c1c)::value;
        bf16x8 bcur[C1];
        {
            const unsigned short* bp = W1ap + ((size_t)s1 * 64 + l) * 8;
            #pragma unroll
            for (int n = 0; n < C1; ++n) bcur[n] = *(const bf16x8*)(bp + n * 512);
        }
        #pragma unroll 1
        for (int kt = 0; kt < 8; ++kt) {
            bf16x8 bnext[C1];
            if (kt + 1 < 8) {
                const unsigned short* bp = W1ap + ((size_t)((kt + 1) * 21 + s1) * 64 + l) * 8;
                #pragma unroll
                for (int n = 0; n < C1; ++n) bnext[n] = *(const bf16x8*)(bp + n * 512);
            }
            bf16x8 af[4];
            #pragma unroll
            for (int mt = 0; mt < 4; ++mt)
                af[mt] = *(const bf16x8*)&smem[(mt * 16 + m16) * 264 + q4 * 8 + kt * 32];
            #pragma unroll
            for (int n = 0; n < C1; ++n)
                #pragma unroll
                for (int mt = 0; mt < 4; ++mt)
                    acc[mt][n] = __builtin_amdgcn_mfma_f32_16x16x32_bf16(af[mt], bcur[n], acc[mt][n], 0, 0, 0);
            #pragma unroll
            for (int n = 0; n < C1; ++n) bcur[n] = bnext[n];
        }
    };
    if (w < 3) run(IC<6>{});
    else       run(IC<3>{});

    // stage bf16 P into LDS [64][344] then contiguous uint4 stores
    __syncthreads();
    {
        const int c1 = (w < 3) ? 6 : 3;
        for (int n = 0; n < c1; ++n) {
            int col = (s1 + n) * 16 + m16;
            float bias = isA ? B1[col] : 0.f;
            #pragma unroll
            for (int mt = 0; mt < 4; ++mt)
                #pragma unroll
                for (int r = 0; r < 4; ++r)
                    smem[(mt * 16 + q4 * 4 + r) * 344 + col] = f2bf(acc[mt][n][r] + bias);
        }
    }
    __syncthreads();
    {
        uint4* dst = (uint4*)(Pp + (size_t)r0 * 336);
        const uint4* src = (const uint4*)smem;
        #pragma unroll 1
        for (int i = t; i < 2688; i += 256)         // 64 rows x 42 uint4
            dst[i] = src[(i / 42) * 43 + (i % 42)]; // LDS stride 344 sh = 43 uint4
    }
}

// ---------------------------------------------------------------------------
// MFMA fused MLP tail. MT=2 (32 rows/block).
// MODE 3: conv: h1 = lrelu(Pab[i]+Pb[j]) by per-thread gather (knn read
//         directly, pad fused, epilogue in disjoint shq) — 2 barriers.
//         4 points/block, 8192 blocks, bounds (256,4). xfl/nrm may be null.
// MODE 2: m1 (K=1056, GEMM1 from xcat) + fused global_mean_pool.
//         1024 blocks, bounds (256,3).
// ---------------------------------------------------------------------------
template<int MODE>
__global__ __launch_bounds__(256, MODE == 3 ? 4 : 3)
void mfma_mlp(const unsigned short* __restrict__ featbf,
              const int* __restrict__ knn,
              const unsigned short* __restrict__ W1p, const float* __restrict__ B1,
              const unsigned short* __restrict__ W2p, const float* __restrict__ B2,
              const unsigned short* __restrict__ Pp,
              const unsigned short* __restrict__ Pbp,
              float* __restrict__ outf,
              unsigned short* __restrict__ xcat, int sliceoff,
              unsigned short* __restrict__ xfl, float* __restrict__ nrm) {
    constexpr int ROWS = 32;

    __shared__ unsigned short smem[ROWS * 360];
    __shared__ unsigned short shq[4 * 512];     // MODE3 epilogue stage (disjoint)
    __shared__ float nparts[4][4];

    const int t = threadIdx.x;
    const int l = t & 63, w = t >> 6;
    const int q4 = l >> 4, m16 = l & 15;
    const int s1 = w * 6;          // GEMM1 ntile start (MODE 2)
    const int s2 = w * 4;          // GEMM2 ntile start (16 total)

    // XCD swizzle: all blocks of a graph share blockIdx%8 -> same XCD L2
    const int bx = blockIdx.x;
    int p0;
    if constexpr (MODE == 3) {
        int slot = bx >> 3;                      // 0..1023
        int g = (bx & 7) + 8 * (slot >> 7);      // graph 0..63
        p0 = g * 512 + (slot & 127) * 4;         // 4 points/block
    } else {
        int slot = bx >> 3;                      // 0..127
        int g = (bx & 7) + 8 * (slot >> 4);      // graph 0..63
        p0 = g * 512 + (slot & 15) * 32;         // 32 rows/block
    }

    if constexpr (MODE == 3) {
        // h1[r][c] = lrelu(Pab[rowi][c] + Pb[rowj][c]) -> bf16 LDS.
        // knn read directly per-thread (8-way L1 broadcast); pad fused.
        const int row = t >> 3;
        const int u0  = t & 7;
        const int pt  = p0 + (row >> 3);
        const int rj  = (pt & ~511) + knn[pt * 8 + (row & 7)];
        const unsigned short* va = Pp  + (size_t)pt * 336;
        const unsigned short* vb = Pbp + (size_t)rj * 336;
        uint4 A[6], Bv[6];
        #pragma unroll
        for (int k = 0; k < 6; ++k) {
            int u = u0 + 8 * k;
            if (u < 42) {
                A[k]  = *(const uint4*)(va + u * 8);
                Bv[k] = *(const uint4*)(vb + u * 8);
            }
        }
        #pragma unroll
        for (int k = 0; k < 6; ++k) {
            int u = u0 + 8 * k;
            if (u < 42) {
                const unsigned* ua = (const unsigned*)&A[k];
                const unsigned* ub = (const unsigned*)&Bv[k];
                uint4 ov;
                unsigned short* o = (unsigned short*)&ov;
                #pragma unroll
                for (int j = 0; j < 4; ++j) {
                    unsigned va_ = ua[j], vb_ = ub[j];
                    float slo = __uint_as_float(va_ << 16) + __uint_as_float(vb_ << 16);
                    float shi = __uint_as_float(va_ & 0xffff0000u) + __uint_as_float(vb_ & 0xffff0000u);
                    o[2 * j]     = f2bf(lrelu(slo));
                    o[2 * j + 1] = f2bf(lrelu(shi));
                }
                *(uint4*)&smem[row * 360 + u * 8] = ov;
            } else if (u < 44) {                 // cols 336..351 zero pad
                *(uint4*)&smem[row * 360 + u * 8] = (uint4){0, 0, 0, 0};
            }
        }
    } else {
        f32x4 acc1[2][6];
        #pragma unroll
        for (int mt = 0; mt < 2; ++mt)
            #pragma unroll
            for (int n = 0; n < 6; ++n) acc1[mt][n] = (f32x4){0.f, 0.f, 0.f, 0.f};

        auto g1 = [&](auto c1c, int ktbase) {
            constexpr int C1 = decltype(c1c)::value;
            bf16x8 bcur[C1];
            {
                const unsigned short* bp =
                    W1p + ((size_t)(ktbase * 21 + s1) * 64 + l) * 8;
                #pragma unroll
                for (int n = 0; n < C1; ++n) bcur[n] = *(const bf16x8*)(bp + n * 512);
            }
            #pragma unroll 1
            for (int kt = 0; kt < 11; ++kt) {
                bf16x8 bnext[C1];
                if (kt + 1 < 11) {
                    const unsigned short* bp =
                        W1p + ((size_t)((ktbase + kt + 1) * 21 + s1) * 64 + l) * 8;
                    #pragma unroll
                    for (int n = 0; n < C1; ++n) bnext[n] = *(const bf16x8*)(bp + n * 512);
                }
                bf16x8 af[2];
                #pragma unroll
                for (int mt = 0; mt < 2; ++mt)
                    af[mt] = *(const bf16x8*)&smem[(mt * 16 + m16) * 360 + q4 * 8 + kt * 32];
                #pragma unroll
                for (int n = 0; n < C1; ++n)
                    #pragma unroll
                    for (int mt = 0; mt < 2; ++mt)
                        acc1[mt][n] = __builtin_amdgcn_mfma_f32_16x16x32_bf16(af[mt], bcur[n], acc1[mt][n], 0, 0, 0);
                #pragma unroll
                for (int n = 0; n < C1; ++n) bcur[n] = bnext[n];
            }
        };

        for (int kc = 0; kc < 3; ++kc) {
            __syncthreads();
            {
                // 32 rows, 8 threads/row, 44 uint4 per row-chunk
                const int r = t >> 3, tc = t & 7;
                const unsigned short* srow =
                    featbf + (size_t)(p0 + r) * 1056 + kc * 352;
                #pragma unroll
                for (int s = 0; s < 6; ++s) {
                    int c16 = tc + (s << 3);
                    if (c16 < 44)
                        *(uint4*)&smem[r * 360 + c16 * 8] = *(const uint4*)(srow + c16 * 8);
                }
            }
            __syncthreads();

            if (w < 3) g1(IC<6>{}, kc * 11);
            else       g1(IC<3>{}, kc * 11);
        }
        __syncthreads();

        // h1 = lrelu(acc1 + b1) -> bf16 LDS [32][360]
        {
            const int c1 = (w < 3) ? 6 : 3;
            for (int n = 0; n < c1; ++n) {
                int nt = s1 + n;
                float b = B1[nt * 16 + m16];
                #pragma unroll
                for (int mt = 0; mt < 2; ++mt) {
                    #pragma unroll
                    for (int r = 0; r < 4; ++r) {
                        int row = mt * 16 + q4 * 4 + r;
                        float v = acc1[mt][n][r] + b;
                        smem[row * 360 + nt * 16 + m16] = f2bf(lrelu(v));
                    }
                }
            }
        }
        if (t < ROWS) {
            #pragma unroll
            for (int c = 336; c < 352; ++c) smem[t * 360 + c] = 0;
        }
    }

    __syncthreads();   // h1 (incl. pad) ready

    // GEMM2: h1[32][352] x W2 slice (4 ntiles per wave), 2-deep B prefetch
    f32x4 acc2[2][4];
    #pragma unroll
    for (int mt = 0; mt < 2; ++mt)
        #pragma unroll
        for (int n = 0; n < 4; ++n) acc2[mt][n] = (f32x4){0.f, 0.f, 0.f, 0.f};
    {
        bf16x8 b0[4], b1f[4];
        {
            const unsigned short* bp0 = W2p + ((size_t)s2 * 64 + l) * 8;
            const unsigned short* bp1 = W2p + ((size_t)(16 + s2) * 64 + l) * 8;
            #pragma unroll
            for (int n = 0; n < 4; ++n) {
                b0[n]  = *(const bf16x8*)(bp0 + n * 512);
                b1f[n] = *(const bf16x8*)(bp1 + n * 512);
            }
        }
        #pragma unroll 1
        for (int kt = 0; kt < 11; ++kt) {
            bf16x8 b2[4];
            if (kt + 2 < 11) {
                const unsigned short* bp = W2p + ((size_t)((kt + 2) * 16 + s2) * 64 + l) * 8;
                #pragma unroll
                for (int n = 0; n < 4; ++n) b2[n] = *(const bf16x8*)(bp + n * 512);
            }
            bf16x8 af[2];
            #pragma unroll
            for (int mt = 0; mt < 2; ++mt)
                af[mt] = *(const bf16x8*)&smem[(mt * 16 + m16) * 360 + q4 * 8 + kt * 32];
            #pragma unroll
            for (int n = 0; n < 4; ++n)
                #pragma unroll
                for (int mt = 0; mt < 2; ++mt)
                    acc2[mt][n] = __builtin_amdgcn_mfma_f32_16x16x32_bf16(af[mt], b0[n], acc2[mt][n], 0, 0, 0);
            #pragma unroll
            for (int n = 0; n < 4; ++n) { b0[n] = b1f[n]; b1f[n] = b2[n]; }
        }
    }

    if constexpr (MODE == 3) {
        // max over 8 edges -> stage hi|lo into shq[4][512] (disjoint from
        // h1 -> no barrier needed before writes), then coalesced stores.
        #pragma unroll
        for (int mt = 0; mt < 2; ++mt) {
            float nsum = 0.f;
            int plocal = mt * 2 + (q4 >> 1);
            #pragma unroll
            for (int n = 0; n < 4; ++n) {
                int nt = s2 + n;
                float b = B2[nt * 16 + m16];
                float mv = -3.4e38f;
                #pragma unroll
                for (int r = 0; r < 4; ++r) mv = fmaxf(mv, lrelu(acc2[mt][n][r] + b));
                mv = fmaxf(mv, __shfl_xor(mv, 16, 64));
                if ((q4 & 1) == 0) {
                    int col = nt * 16 + m16;
                    unsigned short hi = f2bf(mv);
                    float fhi = bf2f(hi);
                    unsigned short lo = f2bf(mv - fhi);
                    float xr = fhi + bf2f(lo);
                    nsum += xr * xr;
                    shq[plocal * 512 + col] = hi;
                    shq[plocal * 512 + 256 + col] = lo;
                }
            }
            #pragma unroll
            for (int o = 1; o < 16; o <<= 1) nsum += __shfl_xor(nsum, o, 64);
            if ((q4 & 1) == 0 && m16 == 0) nparts[plocal][w] = nsum;
        }
        __syncthreads();   // shq + nparts ready
        {
            int r = t >> 6, cb = (t & 63) * 8;
            int p = p0 + r;
            uint4 v0 = *(uint4*)&shq[r * 512 + cb];
            if (xfl)
                *(uint4*)&xfl[(size_t)p * 512 + cb] = v0;
            if (cb < 256)
                *(uint4*)&xcat[(size_t)p * 1056 + sliceoff + cb] = v0;
        }
        if (nrm && t < 4)
            nrm[p0 + t] =
                nparts[t][0] + nparts[t][1] + nparts[t][2] + nparts[t][3];
    } else {
        // fused global_mean_pool: per-block 32-row partial sums -> atomicAdd
        const int bgraph = p0 >> 9;
        #pragma unroll
        for (int n = 0; n < 4; ++n) {
            int nt = s2 + n;
            float b = B2[nt * 16 + m16];
            float s = 0.f;
            #pragma unroll
            for (int mt = 0; mt < 2; ++mt)
                #pragma unroll
                for (int r = 0; r < 4; ++r)
                    s += lrelu(acc2[mt][n][r] + b);
            s += __shfl_xor(s, 16, 64);
            s += __shfl_xor(s, 32, 64);
            if (q4 == 0)
                atomicAdd(outf + bgraph * 256 + nt * 16 + m16, s * (1.f / 512.f));
        }
    }
}

// ---------------------------------------------------------------------------
__global__ __launch_bounds__(128) void head_kernel(const float* __restrict__ g,
                                                   const float* __restrict__ w1,
                                                   const float* __restrict__ b1,
                                                   const float* __restrict__ w2,
                                                   const float* __restrict__ b2,
                                                   float* __restrict__ out) {
    __shared__ float gs[256];
    __shared__ float hid[128];
    int b = blockIdx.x, t = threadIdx.x;
    gs[t] = g[b * 256 + t];
    gs[t + 128] = g[b * 256 + t + 128];
    __syncthreads();
    float s = b1[t];
    for (int c = 0; c < 256; ++c) s += gs[c] * w1[c * 128 + t];
    hid[t] = lrelu(s);
    __syncthreads();
    if (t < 3) {
        float o = b2[t];
        for (int j = 0; j < 128; ++j) o += hid[j] * w2[j * 3 + t];
        out[b * 3 + t] = o;
    }
}

// ---------------------------------------------------------------------------
extern "C" void kernel_launch(void* const* d_in, const int* in_sizes, int n_in,
                              void* d_out, int out_size, void* d_ws, size_t ws_size,
                              hipStream_t stream) {
    const float* xb = (const float*)d_in[0];
    const float* c_w1[4] = { (const float*)d_in[3],  (const float*)d_in[7],
                             (const float*)d_in[11], (const float*)d_in[15] };
    const float* c_b1[4] = { (const float*)d_in[4],  (const float*)d_in[8],
                             (const float*)d_in[12], (const float*)d_in[16] };
    const float* c_w2[4] = { (const float*)d_in[5],  (const float*)d_in[9],
                             (const float*)d_in[13], (const float*)d_in[17] };
    const float* c_b2[4] = { (const float*)d_in[6],  (const float*)d_in[10],
                             (const float*)d_in[14], (const float*)d_in[18] };
    const float* m1w1 = (const float*)d_in[19];
    const float* m1b1 = (const float*)d_in[20];
    const float* m1w2 = (const float*)d_in[21];
    const float* m1b2 = (const float*)d_in[22];
    const float* m2w1 = (const float*)d_in[23];
    const float* m2b1 = (const float*)d_in[24];
    const float* m2w2 = (const float*)d_in[25];
    const float* m2b2 = (const float*)d_in[26];

    char* base = (char*)d_ws;
    size_t off = 0;
    auto alloc = [&](size_t bytes) { char* p = base + off; off = (off + bytes + 255) & ~(size_t)255; return p; };
    int*            knn   = (int*)           alloc((size_t)32768 * 8 * 4);
    float*          nrm   = (float*)         alloc((size_t)32768 * 4);
    char*           Preg  =                  alloc((size_t)32768 * 256 * 4); // Pa bf16 (22MB)
    unsigned short* Ppb   = (unsigned short*)alloc((size_t)32768 * 336 * 2); // Pb bf16 (22MB)
    float*          g     = (float*)         alloc(64 * 256 * 4);
    unsigned short* xcat  = (unsigned short*)alloc((size_t)32768 * 1056 * 2);
    unsigned short* xfl   = (unsigned short*)alloc((size_t)32768 * 512 * 2);
    unsigned short* w1p1  = (unsigned short*)alloc((size_t)1  * 21 * 512 * 2);  // legacy, unused
    unsigned short* w2p1  = (unsigned short*)alloc((size_t)11 * 16 * 512 * 2);
    unsigned short* w1a[3]; unsigned short* w1b[3]; unsigned short* w2p[3];
    for (int i = 0; i < 3; ++i) {
        w1a[i] = (unsigned short*)alloc((size_t)8  * 21 * 512 * 2);
        w1b[i] = (unsigned short*)alloc((size_t)8  * 21 * 512 * 2);
        w2p[i] = (unsigned short*)alloc((size_t)11 * 16 * 512 * 2);
    }
    unsigned short* m1p1  = (unsigned short*)alloc((size_t)33 * 21 * 512 * 2);
    unsigned short* m1p2  = (unsigned short*)alloc((size_t)11 * 16 * 512 * 2);
    unsigned short* Pp = (unsigned short*)Preg;  // bf16 Pa (+b1)

    PTable tb;
    tb.d[0] = { c_w1[0], w1p1, 1,  21, 336, 1, 16,  6,   0   };
    tb.d[1] = { c_w2[0], w2p1, 11, 16, 256, 0, 0,   0,   336 };
    for (int i = 0; i < 3; ++i) {
        tb.d[2 + 3 * i] = { c_w1[i + 1], w1a[i], 8,  21, 336, 1, 0,   256, 0   };
        tb.d[3 + 3 * i] = { c_w1[i + 1], w1b[i], 8,  21, 336, 3, 256, 0,   0   };
        tb.d[4 + 3 * i] = { c_w2[i + 1], w2p[i], 11, 16, 256, 0, 0,   0,   336 };
    }
    tb.d[11] = { m1w1, m1p1, 33, 21, 336, 2, 0, 0, 0   };
    tb.d[12] = { m1w2, m1p2, 11, 16, 256, 0, 0, 0, 336 };
    pack_kernel<<<dim3(1386, 13), dim3(256), 0, stream>>>(tb);
    xbprep_kernel<<<128, 256, 0, stream>>>(xb, xcat, g, nrm);

    // layer 1 (F=6): fp32 kNN on xb; point-factored conv via pgemm1 + MODE 3
    knn_kernel<6><<<1024, 256, 0, stream>>>(xb, nrm, knn);
    pgemm1_kernel<<<5376, 256, 0, stream>>>(xb, c_w1[0], c_b1[0], Pp, Ppb);
    mfma_mlp<3><<<8192, 256, 0, stream>>>(nullptr, knn,
                                          nullptr, nullptr, w2p1, c_b2[0], Pp, Ppb,
                                          nullptr, xcat, 32, xfl, nrm);

    // layers 2..4: MFMA kNN + dual point-GEMM (Pa+b1, Pb) + factored conv.
    // Layer 4's xfl/nrm outputs are dead (m1 reads xcat only) -> nullptr.
    for (int l = 1; l < 4; ++l) {
        int dstslice = 32 + l * 256;
        bool last = (l == 3);
        knn_mfma<<<512, 256, 0, stream>>>(xfl, nrm, knn);
        pgemm_kernel<<<1024, 256, 0, stream>>>(xfl, w1a[l - 1], w1b[l - 1], c_b1[l], Pp, Ppb);
        mfma_mlp<3><<<8192, 256, 0, stream>>>(nullptr, knn,
                                              nullptr, nullptr, w2p[l - 1], c_b2[l], Pp, Ppb,
                                              nullptr, xcat, dstslice,
                                              last ? nullptr : xfl,
                                              last ? nullptr : nrm);
    }

    // m1 over Xcat with fused global_mean_pool -> g (zeroed in xbprep)
    mfma_mlp<2><<<1024, 256, 0, stream>>>(xcat, nullptr,
                                          m1p1, m1b1, m1p2, m1b2, nullptr, nullptr,
                                          g, nullptr, 0, nullptr, nullptr);

    head_kernel<<<64, 128, 0, stream>>>(g, m2w1, m2b1, m2w2, m2b2, (float*)d_out);
}

// Round 14
// 945.568 us; speedup vs baseline: 1.0126x; 1.0126x over previous
//
#include <hip/hip_runtime.h>
#include <hip/hip_bf16.h>

// FINAL (R26 = exact R24 config, best verified 950.7us; 1443.8 -> 950.7).
// B=64 graphs, N=512 pts, F0=6, K=8, conv out C=256, hidden H=336,
// m1 in 1030 (pad->1056), head 256->128->3.  fp32 in/out.
// Win ledger: R14 xj-factorization (edge GEMM1 -> per-point Pa/Pb, -28%);
// R19 layer-1 point factorization (killed MODE1's pathological ~1GB/dispatch
// traffic); R20 knn Q-hoist to VGPR + pool fused into MODE2; R24 norms fused
// into xbprep. Measured-dead dials: occupancy forcing (spills: R13/R21/R22),
// dispatch fusion (R16/R17/R21/R23), latency micro-opts (R15/R25 null —
// conv is gather-latency + VALU-unpack bound at its reg-feasible occupancy).

#define DEVFN __device__ __forceinline__
DEVFN float lrelu(float v) { return fmaxf(v, 0.01f * v); }

using bf16x8 = __attribute__((ext_vector_type(8))) short;
using f32x4  = __attribute__((ext_vector_type(4))) float;

template<int N> struct IC { static constexpr int value = N; };

DEVFN unsigned short f2bf(float v) {
    __hip_bfloat16 h = __float2bfloat16(v);
    return *(unsigned short*)&h;
}
DEVFN float bf2f(unsigned short u) {
    return __uint_as_float((unsigned)u << 16);
}

// ---------------------------------------------------------------------------
// weight packing: fp32 [K][N] -> bf16 B-fragment layout [kt][nt][lane][8]
// ---------------------------------------------------------------------------
struct PDesc { const float* src; unsigned short* dst; int Kt, NT, N, mode, p0, p1, Ksrc; };
struct PTable { PDesc d[13]; };

__global__ __launch_bounds__(256) void pack_kernel(PTable tb) {
    PDesc d = tb.d[blockIdx.y];
    int i = blockIdx.x * 256 + threadIdx.x;
    int tot = d.Kt * d.NT * 512;
    if (i >= tot) return;
    int j = i & 7, lane = (i >> 3) & 63;
    int tile = i >> 9;
    int nt = tile % d.NT, kt = tile / d.NT;
    int k = kt * 32 + ((lane >> 4) << 3) + j;
    int n = nt * 16 + (lane & 15);
    float v = 0.f;
    if (d.mode == 0) {
        if (k < d.Ksrc) v = d.src[(size_t)k * d.N + n];
    } else if (d.mode == 1) {
        if (k < d.p1) v = d.src[(size_t)k * d.N + n] - d.src[(size_t)(k + d.p1) * d.N + n];
        else if (k >= d.p0 && k < d.p0 + d.p1) v = d.src[(size_t)(k - d.p0 + d.p1) * d.N + n];
    } else if (d.mode == 2) {
        if (k < 6) v = d.src[(size_t)k * d.N + n];
        else if (k >= 32 && k < 1056) v = d.src[(size_t)(k - 26) * d.N + n];
    } else {
        v = d.src[(size_t)(k + d.p0) * d.N + n];
    }
    d.dst[i] = f2bf(v);
}

// ---------------------------------------------------------------------------
// xbprep: bf16 xb into xcat slice 0, zero pooled output, layer-1 norms.
// ---------------------------------------------------------------------------
__global__ __launch_bounds__(256) void xbprep_kernel(const float* __restrict__ xb,
                                                     unsigned short* __restrict__ xcat,
                                                     float* __restrict__ g,
                                                     float* __restrict__ nrm) {
    int p = blockIdx.x * 256 + threadIdx.x;
    if (p >= 32768) return;
    if (p < 16384) g[p] = 0.f;      // zero pooled output (MODE2 atomicAdds)
    unsigned short r[16];
    float s = 0.f;
    #pragma unroll
    for (int c = 0; c < 6; ++c) {
        float v = xb[p * 6 + c];
        s += v * v;
        r[c] = f2bf(v);
    }
    nrm[p] = s;
    #pragma unroll
    for (int c = 6; c < 16; ++c) r[c] = 0;
    unsigned short* xc = xcat + (size_t)p * 1056;
    #pragma unroll
    for (int c = 0; c < 16; ++c) xc[c] = r[c];
    #pragma unroll
    for (int c = 16; c < 32; ++c) xc[c] = 0;
}

// ---------------------------------------------------------------------------
// kNN fp32 (layer 1, F=6): 32 queries/block, stable top-8
// ---------------------------------------------------------------------------
template<int F>
__global__ __launch_bounds__(256) void knn_kernel(const float* __restrict__ feat,
                                                  const float* __restrict__ nrm,
                                                  int* __restrict__ knn) {
    constexpr int FP = (F == 6) ? 8 : (F + 4);
    __shared__ float Xq[32 * FP];
    __shared__ float Xc[32 * FP];
    __shared__ float qn[32], cn[32];
    __shared__ float dt[32 * 33];
    const int t  = threadIdx.x;
    const int b  = blockIdx.x >> 4;
    const int n0 = (blockIdx.x & 15) << 5;
    const float* fg = feat + (size_t)b * 512 * F;

    for (int i = t; i < 32 * F; i += 256) {
        int r = i / F, c = i - r * F;
        Xq[r * FP + c] = fg[(size_t)(n0 + r) * F + c];
    }
    if (t < 32) qn[t] = nrm[b * 512 + n0 + t];

    float d8[8]; int i8[8];
    #pragma unroll
    for (int k = 0; k < 8; ++k) { d8[k] = 3.4e38f; i8[k] = 0; }

    const int q = t >> 3, cs = t & 7;

    for (int ct = 0; ct < 16; ++ct) {
        const int c0 = ct << 5;
        __syncthreads();
        for (int i = t; i < 32 * F; i += 256) {
            int r = i / F, c = i - r * F;
            Xc[r * FP + c] = fg[(size_t)(c0 + r) * F + c];
        }
        if (t < 32) cn[t] = nrm[b * 512 + c0 + t];
        __syncthreads();

        float acc[4] = {0.f, 0.f, 0.f, 0.f};
        #pragma unroll
        for (int f = 0; f < F; ++f) {
            float qv = Xq[q * FP + f];
            #pragma unroll
            for (int j = 0; j < 4; ++j) acc[j] += qv * Xc[(cs + 8 * j) * FP + f];
        }
        #pragma unroll
        for (int j = 0; j < 4; ++j)
            dt[q * 33 + cs + 8 * j] = qn[q] + cn[cs + 8 * j] - 2.f * acc[j];
        __syncthreads();

        if (t < 32) {
            #pragma unroll 1
            for (int i = 0; i < 32; ++i) {
                float d = dt[t * 33 + i];
                if (d < d8[7]) {
                    d8[7] = d; i8[7] = c0 + i;
                    #pragma unroll
                    for (int s = 7; s >= 1; --s) {
                        if (d8[s] < d8[s - 1]) {
                            float td = d8[s]; d8[s] = d8[s - 1]; d8[s - 1] = td;
                            int   ti = i8[s]; i8[s] = i8[s - 1]; i8[s - 1] = ti;
                        }
                    }
                }
            }
        }
    }
    if (t < 32) {
        #pragma unroll
        for (int k = 0; k < 8; ++k)
            knn[((size_t)b * 512 + n0 + t) * 8 + k] = i8[k];
    }
}

// ---------------------------------------------------------------------------
// kNN via MFMA Gram (bf16x3), layers 2-4. Reads xfl (hi|lo, stride 512).
// R20: Q fragments live in 64 VGPR; only C tiles are LDS-staged.
// ---------------------------------------------------------------------------
__global__ __launch_bounds__(256, 2)
void knn_mfma(const unsigned short* __restrict__ xfl,
              const float* __restrict__ nrm,
              int* __restrict__ knn) {
    __shared__ unsigned short Ch[64 * 72], Cl[64 * 72];
    __shared__ float dt[64 * 66];
    __shared__ float qn[64], cn[64];
    float* mD = dt;
    int*   mI = (int*)(dt + 2048);

    const int t  = threadIdx.x;
    const int l  = t & 63, w = t >> 6;
    const int m16 = l & 15, q4 = l >> 4;
    const int bx = blockIdx.x;
    const int slot = bx >> 3;
    const int b  = (bx & 7) + 8 * (slot >> 3);   // graph: all its blocks on one XCD
    const int qs = (slot & 7) << 6;

    if (t < 64) qn[t] = nrm[b * 512 + qs + t];

    // Q fragments in registers: this lane's row (qs + w*16 + m16), all 512 k.
    bf16x8 qh[4][2], ql[4][2];
    {
        const unsigned short* qr = xfl + (size_t)(b * 512 + qs + w * 16 + m16) * 512;
        #pragma unroll
        for (int kc = 0; kc < 4; ++kc)
            #pragma unroll
            for (int kt = 0; kt < 2; ++kt) {
                qh[kc][kt] = *(const bf16x8*)(qr + kc * 64 + kt * 32 + q4 * 8);
                ql[kc][kt] = *(const bf16x8*)(qr + 256 + kc * 64 + kt * 32 + q4 * 8);
            }
    }

    float d8[8]; int i8[8];
    #pragma unroll
    for (int k = 0; k < 8; ++k) { d8[k] = 3.4e38f; i8[k] = 0x7fffffff; }

    const int sr = t >> 2;
    const int sc = (t & 3) << 4;
    const int tq = t & 63, sub = t >> 6;

    for (int cs = 0; cs < 8; ++cs) {
        const int c0 = cs << 6;
        if (t < 64) cn[t] = nrm[b * 512 + c0 + t];

        f32x4 acc[4];
        #pragma unroll
        for (int i = 0; i < 4; ++i) acc[i] = (f32x4){0.f, 0.f, 0.f, 0.f};

        #pragma unroll
        for (int kc = 0; kc < 4; ++kc) {
            const int k0 = kc << 6;
            __syncthreads();
            {
                const unsigned short* cr = xfl + (size_t)(b * 512 + c0 + sr) * 512;
                *(uint4*)&Ch[sr * 72 + sc]     = *(const uint4*)(cr + k0 + sc);
                *(uint4*)&Ch[sr * 72 + sc + 8] = *(const uint4*)(cr + k0 + sc + 8);
                *(uint4*)&Cl[sr * 72 + sc]     = *(const uint4*)(cr + 256 + k0 + sc);
                *(uint4*)&Cl[sr * 72 + sc + 8] = *(const uint4*)(cr + 256 + k0 + sc + 8);
            }
            __syncthreads();

            #pragma unroll
            for (int kt = 0; kt < 2; ++kt) {
                const int ko = kt * 32 + q4 * 8;
                bf16x8 ah = qh[kc][kt];
                bf16x8 al = ql[kc][kt];
                #pragma unroll
                for (int nt = 0; nt < 4; ++nt) {
                    bf16x8 bh = *(const bf16x8*)&Ch[(nt * 16 + m16) * 72 + ko];
                    bf16x8 bl = *(const bf16x8*)&Cl[(nt * 16 + m16) * 72 + ko];
                    acc[nt] = __builtin_amdgcn_mfma_f32_16x16x32_bf16(ah, bh, acc[nt], 0, 0, 0);
                    acc[nt] = __builtin_amdgcn_mfma_f32_16x16x32_bf16(ah, bl, acc[nt], 0, 0, 0);
                    acc[nt] = __builtin_amdgcn_mfma_f32_16x16x32_bf16(al, bh, acc[nt], 0, 0, 0);
                }
            }
        }

        #pragma unroll
        for (int nt = 0; nt < 4; ++nt) {
            float cv = cn[nt * 16 + m16];
            #pragma unroll
            for (int rr = 0; rr < 4; ++rr) {
                int qr = w * 16 + q4 * 4 + rr;
                dt[qr * 66 + nt * 16 + m16] = qn[qr] + cv - 2.f * acc[nt][rr];
            }
        }
        __syncthreads();

        {
            const float* drow = &dt[tq * 66 + sub * 16];
            #pragma unroll 1
            for (int j = 0; j < 16; ++j) {
                float d = drow[j];
                if (d < d8[7]) {
                    d8[7] = d; i8[7] = c0 + sub * 16 + j;
                    #pragma unroll
                    for (int s = 7; s >= 1; --s) {
                        if (d8[s] < d8[s - 1]) {
                            float td = d8[s]; d8[s] = d8[s - 1]; d8[s - 1] = td;
                            int   ti = i8[s]; i8[s] = i8[s - 1]; i8[s - 1] = ti;
                        }
                    }
                }
            }
        }
        __syncthreads();
    }

    #pragma unroll
    for (int k = 0; k < 8; ++k) {
        mD[(tq * 4 + sub) * 8 + k] = d8[k];
        mI[(tq * 4 + sub) * 8 + k] = i8[k];
    }
    __syncthreads();
    if (t < 64) {
        int p[4] = {0, 0, 0, 0};
        int outb = (b * 512 + qs + t) * 8;
        #pragma unroll 1
        for (int k = 0; k < 8; ++k) {
            float bd = 3.5e38f; int bi = 0x7fffffff; int bs = 0;
            #pragma unroll
            for (int s = 0; s < 4; ++s) {
                if (p[s] < 8) {
                    float dd = mD[(t * 4 + s) * 8 + p[s]];
                    int   ii = mI[(t * 4 + s) * 8 + p[s]];
                    if (dd < bd || (dd == bd && ii < bi)) { bd = dd; bi = ii; bs = s; }
                }
            }
            knn[outb + k] = bi;
            p[bs]++;
        }
    }
}

// ---------------------------------------------------------------------------
// R19: layer-1 point factorization (VALU, fp32 in -> bf16 P rows).
// ---------------------------------------------------------------------------
__global__ __launch_bounds__(256)
void pgemm1_kernel(const float* __restrict__ xb,
                   const float* __restrict__ W1,
                   const float* __restrict__ B1,
                   unsigned short* __restrict__ Pa,
                   unsigned short* __restrict__ Pb) {
    int i = blockIdx.x * 256 + threadIdx.x;
    if (i >= 32768 * 42) return;
    int p = i / 42, c8 = i - p * 42;
    int c0 = c8 * 8;
    float x[6];
    #pragma unroll
    for (int k = 0; k < 6; ++k) x[k] = xb[p * 6 + k];
    float sa[8], sb[8];
    #pragma unroll
    for (int j = 0; j < 8; ++j) { sa[j] = B1[c0 + j]; sb[j] = 0.f; }
    #pragma unroll
    for (int k = 0; k < 6; ++k) {
        const float* wra = W1 + (size_t)k * 336 + c0;
        const float* wrb = W1 + (size_t)(k + 6) * 336 + c0;
        #pragma unroll
        for (int j = 0; j < 8; ++j) {
            float wb = wrb[j];
            sa[j] += x[k] * (wra[j] - wb);
            sb[j] += x[k] * wb;
        }
    }
    unsigned short oa[8], ob[8];
    #pragma unroll
    for (int j = 0; j < 8; ++j) { oa[j] = f2bf(sa[j]); ob[j] = f2bf(sb[j]); }
    *(uint4*)&Pa[(size_t)p * 336 + c0] = *(uint4*)oa;
    *(uint4*)&Pb[(size_t)p * 336 + c0] = *(uint4*)ob;
}

// ---------------------------------------------------------------------------
// Point-GEMM dual: Pa = x_hi @ W1a + b1 (bias folded) and Pb = x_hi @ W1b
// (32768 x 336, K=256), 64 points/block.  (256,3).
// ---------------------------------------------------------------------------
__global__ __launch_bounds__(256, 3)
void pgemm_kernel(const unsigned short* __restrict__ xfl,
                  const unsigned short* __restrict__ Wa,
                  const unsigned short* __restrict__ Wb,
                  const float* __restrict__ B1,
                  unsigned short* __restrict__ Pa,
                  unsigned short* __restrict__ Pb) {
    __shared__ unsigned short smem[64 * 344];   // A-chunk (stride 264) / P-stage (stride 344)
    const int t = threadIdx.x;
    const int l = t & 63, w = t >> 6;
    const int q4 = l >> 4, m16 = l & 15;
    const int s1 = w * 6;
    const int bx = blockIdx.x & 511;
    const bool isA = !(blockIdx.x & 512);
    const unsigned short* W1ap = isA ? Wa : Wb;
    unsigned short*       Pp   = isA ? Pa : Pb;
    const int slot = bx >> 3;
    const int r0 = ((bx & 7) + 8 * (slot >> 3)) * 512 + (slot & 7) * 64;

    {
        const int r = t >> 2;
        const unsigned short* srow = xfl + (size_t)(r0 + r) * 512;
        #pragma unroll
        for (int s = 0; s < 8; ++s) {
            int c16 = (t & 3) + (s << 2);
            *(uint4*)&smem[r * 264 + c16 * 8] = *(const uint4*)(srow + c16 * 8);
        }
    }
    __syncthreads();

    f32x4 acc[4][6];
    #pragma unroll
    for (int mt = 0; mt < 4; ++mt)
        #pragma unroll
        for (int n = 0; n < 6; ++n) acc[mt][n] = (f32x4){0.f, 0.f, 0.f, 0.f};

    auto run = [&](auto c1c) {
        constexpr int C1 = decltype(c1c)::value;
        bf16x8 bcur[C1];
        {
            const unsigned short* bp = W1ap + ((size_t)s1 * 64 + l) * 8;
            #pragma unroll
            for (int n = 0; n < C1; ++n) bcur[n] = *(const bf16x8*)(bp + n * 512);
        }
        #pragma unroll 1
        for (int kt = 0; kt < 8; ++kt) {
            bf16x8 bnext[C1];
            if (kt + 1 < 8) {
                const unsigned short* bp = W1ap + ((size_t)((kt + 1) * 21 + s1) * 64 + l) * 8;
                #pragma unroll
                for (int n = 0; n < C1; ++n) bnext[n] = *(const bf16x8*)(bp + n * 512);
            }
            bf16x8 af[4];
            #pragma unroll
            for (int mt = 0; mt < 4; ++mt)
                af[mt] = *(const bf16x8*)&smem[(mt * 16 + m16) * 264 + q4 * 8 + kt * 32];
            #pragma unroll
            for (int n = 0; n < C1; ++n)
                #pragma unroll
                for (int mt = 0; mt < 4; ++mt)
                    acc[mt][n] = __builtin_amdgcn_mfma_f32_16x16x32_bf16(af[mt], bcur[n], acc[mt][n], 0, 0, 0);
            #pragma unroll
            for (int n = 0; n < C1; ++n) bcur[n] = bnext[n];
        }
    };
    if (w < 3) run(IC<6>{});
    else       run(IC<3>{});

    // stage bf16 P into LDS [64][344] then contiguous uint4 stores
    __syncthreads();
    {
        const int c1 = (w < 3) ? 6 : 3;
        for (int n = 0; n < c1; ++n) {
            int col = (s1 + n) * 16 + m16;
            float bias = isA ? B1[col] : 0.f;
            #pragma unroll
            for (int mt = 0; mt < 4; ++mt)
                #pragma unroll
                for (int r = 0; r < 4; ++r)
                    smem[(mt * 16 + q4 * 4 + r) * 344 + col] = f2bf(acc[mt][n][r] + bias);
        }
    }
    __syncthreads();
    {
        uint4* dst = (uint4*)(Pp + (size_t)r0 * 336);
        const uint4* src = (const uint4*)smem;
        #pragma unroll 1
        for (int i = t; i < 2688; i += 256)         // 64 rows x 42 uint4
            dst[i] = src[(i / 42) * 43 + (i % 42)]; // LDS stride 344 sh = 43 uint4
    }
}

// ---------------------------------------------------------------------------
// MFMA fused MLP tail. MT=2 (32 rows/block).
// MODE 3: conv (all 4 layers): h1 = lrelu(Pab[i]+Pb[j]) by gather,
//         GEMM2 + edge-max. 4 points/block, 8192 blocks, bounds (256,4).
// MODE 2: m1 (K=1056, GEMM1 from xcat) + fused global_mean_pool.
//         1024 blocks, bounds (256,3).
// ---------------------------------------------------------------------------
template<int MODE>
__global__ __launch_bounds__(256, MODE == 3 ? 4 : 3)
void mfma_mlp(const unsigned short* __restrict__ featbf,
              const int* __restrict__ knn,
              const unsigned short* __restrict__ W1p, const float* __restrict__ B1,
              const unsigned short* __restrict__ W2p, const float* __restrict__ B2,
              const unsigned short* __restrict__ Pp,
              const unsigned short* __restrict__ Pbp,
              float* __restrict__ outf,
              unsigned short* __restrict__ xcat, int sliceoff,
              unsigned short* __restrict__ xfl, float* __restrict__ nrm) {
    constexpr int ROWS = 32;

    __shared__ unsigned short smem[ROWS * 360];
    __shared__ int rowi[32];
    __shared__ int rowj[32];
    __shared__ float nparts[4][4];

    const int t = threadIdx.x;
    const int l = t & 63, w = t >> 6;
    const int q4 = l >> 4, m16 = l & 15;
    const int s1 = w * 6;          // GEMM1 ntile start (MODE 2)
    const int s2 = w * 4;          // GEMM2 ntile start (16 total)

    // XCD swizzle: all blocks of a graph share blockIdx%8 -> same XCD L2
    const int bx = blockIdx.x;
    int p0;
    if constexpr (MODE == 3) {
        int slot = bx >> 3;                      // 0..1023
        int g = (bx & 7) + 8 * (slot >> 7);      // graph 0..63
        p0 = g * 512 + (slot & 127) * 4;         // 4 points/block
    } else {
        int slot = bx >> 3;                      // 0..127
        int g = (bx & 7) + 8 * (slot >> 4);      // graph 0..63
        p0 = g * 512 + (slot & 15) * 32;         // 32 rows/block
    }

    if constexpr (MODE == 3) {
        if (t < 32) {
            int pt = p0 + (t >> 3);
            rowi[t] = pt;
            rowj[t] = (pt & ~511) + knn[pt * 8 + (t & 7)];
        }
        __syncthreads();
        // h1[r][c] = lrelu(Pab[rowi[r]][c] + Pb[rowj[r]][c]) -> bf16 LDS.
        const int row = t >> 3;
        const int u0  = t & 7;
        const unsigned short* va = Pp  + (size_t)rowi[row] * 336;
        const unsigned short* vb = Pbp + (size_t)rowj[row] * 336;
        uint4 A[6], Bv[6];
        #pragma unroll
        for (int k = 0; k < 6; ++k) {
            int u = u0 + 8 * k;
            if (u < 42) {
                A[k]  = *(const uint4*)(va + u * 8);
                Bv[k] = *(const uint4*)(vb + u * 8);
            }
        }
        #pragma unroll
        for (int k = 0; k < 6; ++k) {
            int u = u0 + 8 * k;
            if (u < 42) {
                const unsigned* ua = (const unsigned*)&A[k];
                const unsigned* ub = (const unsigned*)&Bv[k];
                uint4 ov;
                unsigned short* o = (unsigned short*)&ov;
                #pragma unroll
                for (int j = 0; j < 4; ++j) {
                    unsigned va_ = ua[j], vb_ = ub[j];
                    float slo = __uint_as_float(va_ << 16) + __uint_as_float(vb_ << 16);
                    float shi = __uint_as_float(va_ & 0xffff0000u) + __uint_as_float(vb_ & 0xffff0000u);
                    o[2 * j]     = f2bf(lrelu(slo));
                    o[2 * j + 1] = f2bf(lrelu(shi));
                }
                *(uint4*)&smem[row * 360 + u * 8] = ov;
            }
        }
    } else {
        f32x4 acc1[2][6];
        #pragma unroll
        for (int mt = 0; mt < 2; ++mt)
            #pragma unroll
            for (int n = 0; n < 6; ++n) acc1[mt][n] = (f32x4){0.f, 0.f, 0.f, 0.f};

        auto g1 = [&](auto c1c, int ktbase) {
            constexpr int C1 = decltype(c1c)::value;
            bf16x8 bcur[C1];
            {
                const unsigned short* bp =
                    W1p + ((size_t)(ktbase * 21 + s1) * 64 + l) * 8;
                #pragma unroll
                for (int n = 0; n < C1; ++n) bcur[n] = *(const bf16x8*)(bp + n * 512);
            }
            #pragma unroll 1
            for (int kt = 0; kt < 11; ++kt) {
                bf16x8 bnext[C1];
                if (kt + 1 < 11) {
                    const unsigned short* bp =
                        W1p + ((size_t)((ktbase + kt + 1) * 21 + s1) * 64 + l) * 8;
                    #pragma unroll
                    for (int n = 0; n < C1; ++n) bnext[n] = *(const bf16x8*)(bp + n * 512);
                }
                bf16x8 af[2];
                #pragma unroll
                for (int mt = 0; mt < 2; ++mt)
                    af[mt] = *(const bf16x8*)&smem[(mt * 16 + m16) * 360 + q4 * 8 + kt * 32];
                #pragma unroll
                for (int n = 0; n < C1; ++n)
                    #pragma unroll
                    for (int mt = 0; mt < 2; ++mt)
                        acc1[mt][n] = __builtin_amdgcn_mfma_f32_16x16x32_bf16(af[mt], bcur[n], acc1[mt][n], 0, 0, 0);
                #pragma unroll
                for (int n = 0; n < C1; ++n) bcur[n] = bnext[n];
            }
        };

        for (int kc = 0; kc < 3; ++kc) {
            __syncthreads();
            {
                // 32 rows, 8 threads/row, 44 uint4 per row-chunk
                const int r = t >> 3, tc = t & 7;
                const unsigned short* srow =
                    featbf + (size_t)(p0 + r) * 1056 + kc * 352;
                #pragma unroll
                for (int s = 0; s < 6; ++s) {
                    int c16 = tc + (s << 3);
                    if (c16 < 44)
                        *(uint4*)&smem[r * 360 + c16 * 8] = *(const uint4*)(srow + c16 * 8);
                }
            }
            __syncthreads();

            if (w < 3) g1(IC<6>{}, kc * 11);
            else       g1(IC<3>{}, kc * 11);
        }
        __syncthreads();

        // h1 = lrelu(acc1 + b1) -> bf16 LDS [32][360]
        {
            const int c1 = (w < 3) ? 6 : 3;
            for (int n = 0; n < c1; ++n) {
                int nt = s1 + n;
                float b = B1[nt * 16 + m16];
                #pragma unroll
                for (int mt = 0; mt < 2; ++mt) {
                    #pragma unroll
                    for (int r = 0; r < 4; ++r) {
                        int row = mt * 16 + q4 * 4 + r;
                        float v = acc1[mt][n][r] + b;
                        smem[row * 360 + nt * 16 + m16] = f2bf(lrelu(v));
                    }
                }
            }
        }
    }

    if (t < ROWS) {
        #pragma unroll
        for (int c = 336; c < 352; ++c) smem[t * 360 + c] = 0;
    }
    __syncthreads();

    // GEMM2: h1[32][352] x W2 slice (4 ntiles per wave), 2-deep B prefetch
    f32x4 acc2[2][4];
    #pragma unroll
    for (int mt = 0; mt < 2; ++mt)
        #pragma unroll
        for (int n = 0; n < 4; ++n) acc2[mt][n] = (f32x4){0.f, 0.f, 0.f, 0.f};
    {
        bf16x8 b0[4], b1f[4];
        {
            const unsigned short* bp0 = W2p + ((size_t)s2 * 64 + l) * 8;
            const unsigned short* bp1 = W2p + ((size_t)(16 + s2) * 64 + l) * 8;
            #pragma unroll
            for (int n = 0; n < 4; ++n) {
                b0[n]  = *(const bf16x8*)(bp0 + n * 512);
                b1f[n] = *(const bf16x8*)(bp1 + n * 512);
            }
        }
        #pragma unroll 1
        for (int kt = 0; kt < 11; ++kt) {
            bf16x8 b2[4];
            if (kt + 2 < 11) {
                const unsigned short* bp = W2p + ((size_t)((kt + 2) * 16 + s2) * 64 + l) * 8;
                #pragma unroll
                for (int n = 0; n < 4; ++n) b2[n] = *(const bf16x8*)(bp + n * 512);
            }
            bf16x8 af[2];
            #pragma unroll
            for (int mt = 0; mt < 2; ++mt)
                af[mt] = *(const bf16x8*)&smem[(mt * 16 + m16) * 360 + q4 * 8 + kt * 32];
            #pragma unroll
            for (int n = 0; n < 4; ++n)
                #pragma unroll
                for (int mt = 0; mt < 2; ++mt)
                    acc2[mt][n] = __builtin_amdgcn_mfma_f32_16x16x32_bf16(af[mt], b0[n], acc2[mt][n], 0, 0, 0);
            #pragma unroll
            for (int n = 0; n < 4; ++n) { b0[n] = b1f[n]; b1f[n] = b2[n]; }
        }
    }

    if constexpr (MODE == 3) {
        // max over 8 edges -> stage hi|lo into LDS [4][512], coalesced stores
        __syncthreads();
        unsigned short* sh = smem;
        #pragma unroll
        for (int mt = 0; mt < 2; ++mt) {
            float nsum = 0.f;
            int plocal = mt * 2 + (q4 >> 1);
            #pragma unroll
            for (int n = 0; n < 4; ++n) {
                int nt = s2 + n;
                float b = B2[nt * 16 + m16];
                float mv = -3.4e38f;
                #pragma unroll
                for (int r = 0; r < 4; ++r) mv = fmaxf(mv, lrelu(acc2[mt][n][r] + b));
                mv = fmaxf(mv, __shfl_xor(mv, 16, 64));
                if ((q4 & 1) == 0) {
                    int col = nt * 16 + m16;
                    unsigned short hi = f2bf(mv);
                    float fhi = bf2f(hi);
                    unsigned short lo = f2bf(mv - fhi);
                    float xr = fhi + bf2f(lo);
                    nsum += xr * xr;
                    sh[plocal * 512 + col] = hi;
                    sh[plocal * 512 + 256 + col] = lo;
                }
            }
            #pragma unroll
            for (int o = 1; o < 16; o <<= 1) nsum += __shfl_xor(nsum, o, 64);
            if ((q4 & 1) == 0 && m16 == 0) nparts[plocal][w] = nsum;
        }
        __syncthreads();
        {
            int r = t >> 6, cb = (t & 63) * 8;
            int p = p0 + r;
            uint4 v0 = *(uint4*)&sh[r * 512 + cb];
            if (xfl)
                *(uint4*)&xfl[(size_t)p * 512 + cb] = v0;
            if (cb < 256)
                *(uint4*)&xcat[(size_t)p * 1056 + sliceoff + cb] = v0;
        }
        if (nrm && t < 4)
            nrm[p0 + t] =
                nparts[t][0] + nparts[t][1] + nparts[t][2] + nparts[t][3];
    } else {
        // fused global_mean_pool: per-block 32-row partial sums -> atomicAdd
        const int bgraph = p0 >> 9;
        #pragma unroll
        for (int n = 0; n < 4; ++n) {
            int nt = s2 + n;
            float b = B2[nt * 16 + m16];
            float s = 0.f;
            #pragma unroll
            for (int mt = 0; mt < 2; ++mt)
                #pragma unroll
                for (int r = 0; r < 4; ++r)
                    s += lrelu(acc2[mt][n][r] + b);
            s += __shfl_xor(s, 16, 64);
            s += __shfl_xor(s, 32, 64);
            if (q4 == 0)
                atomicAdd(outf + bgraph * 256 + nt * 16 + m16, s * (1.f / 512.f));
        }
    }
}

// ---------------------------------------------------------------------------
__global__ __launch_bounds__(128) void head_kernel(const float* __restrict__ g,
                                                   const float* __restrict__ w1,
                                                   const float* __restrict__ b1,
                                                   const float* __restrict__ w2,
                                                   const float* __restrict__ b2,
                                                   float* __restrict__ out) {
    __shared__ float gs[256];
    __shared__ float hid[128];
    int b = blockIdx.x, t = threadIdx.x;
    gs[t] = g[b * 256 + t];
    gs[t + 128] = g[b * 256 + t + 128];
    __syncthreads();
    float s = b1[t];
    for (int c = 0; c < 256; ++c) s += gs[c] * w1[c * 128 + t];
    hid[t] = lrelu(s);
    __syncthreads();
    if (t < 3) {
        float o = b2[t];
        for (int j = 0; j < 128; ++j) o += hid[j] * w2[j * 3 + t];
        out[b * 3 + t] = o;
    }
}

// ---------------------------------------------------------------------------
extern "C" void kernel_launch(void* const* d_in, const int* in_sizes, int n_in,
                              void* d_out, int out_size, void* d_ws, size_t ws_size,
                              hipStream_t stream) {
    const float* xb = (const float*)d_in[0];
    const float* c_w1[4] = { (const float*)d_in[3],  (const float*)d_in[7],
                             (const float*)d_in[11], (const float*)d_in[15] };
    const float* c_b1[4] = { (const float*)d_in[4],  (const float*)d_in[8],
                             (const float*)d_in[12], (const float*)d_in[16] };
    const float* c_w2[4] = { (const float*)d_in[5],  (const float*)d_in[9],
                             (const float*)d_in[13], (const float*)d_in[17] };
    const float* c_b2[4] = { (const float*)d_in[6],  (const float*)d_in[10],
                             (const float*)d_in[14], (const float*)d_in[18] };
    const float* m1w1 = (const float*)d_in[19];
    const float* m1b1 = (const float*)d_in[20];
    const float* m1w2 = (const float*)d_in[21];
    const float* m1b2 = (const float*)d_in[22];
    const float* m2w1 = (const float*)d_in[23];
    const float* m2b1 = (const float*)d_in[24];
    const float* m2w2 = (const float*)d_in[25];
    const float* m2b2 = (const float*)d_in[26];

    char* base = (char*)d_ws;
    size_t off = 0;
    auto alloc = [&](size_t bytes) { char* p = base + off; off = (off + bytes + 255) & ~(size_t)255; return p; };
    int*            knn   = (int*)           alloc((size_t)32768 * 8 * 4);
    float*          nrm   = (float*)         alloc((size_t)32768 * 4);
    char*           Preg  =                  alloc((size_t)32768 * 256 * 4); // Pa bf16 (22MB)
    unsigned short* Ppb   = (unsigned short*)alloc((size_t)32768 * 336 * 2); // Pb bf16 (22MB)
    float*          g     = (float*)         alloc(64 * 256 * 4);
    unsigned short* xcat  = (unsigned short*)alloc((size_t)32768 * 1056 * 2);
    unsigned short* xfl   = (unsigned short*)alloc((size_t)32768 * 512 * 2);
    unsigned short* w1p1  = (unsigned short*)alloc((size_t)1  * 21 * 512 * 2);  // legacy, unused
    unsigned short* w2p1  = (unsigned short*)alloc((size_t)11 * 16 * 512 * 2);
    unsigned short* w1a[3]; unsigned short* w1b[3]; unsigned short* w2p[3];
    for (int i = 0; i < 3; ++i) {
        w1a[i] = (unsigned short*)alloc((size_t)8  * 21 * 512 * 2);
        w1b[i] = (unsigned short*)alloc((size_t)8  * 21 * 512 * 2);
        w2p[i] = (unsigned short*)alloc((size_t)11 * 16 * 512 * 2);
    }
    unsigned short* m1p1  = (unsigned short*)alloc((size_t)33 * 21 * 512 * 2);
    unsigned short* m1p2  = (unsigned short*)alloc((size_t)11 * 16 * 512 * 2);
    unsigned short* Pp = (unsigned short*)Preg;  // bf16 Pa (+b1)

    PTable tb;
    tb.d[0] = { c_w1[0], w1p1, 1,  21, 336, 1, 16,  6,   0   };
    tb.d[1] = { c_w2[0], w2p1, 11, 16, 256, 0, 0,   0,   336 };
    for (int i = 0; i < 3; ++i) {
        tb.d[2 + 3 * i] = { c_w1[i + 1], w1a[i], 8,  21, 336, 1, 0,   256, 0   };
        tb.d[3 + 3 * i] = { c_w1[i + 1], w1b[i], 8,  21, 336, 3, 256, 0,   0   };
        tb.d[4 + 3 * i] = { c_w2[i + 1], w2p[i], 11, 16, 256, 0, 0,   0,   336 };
    }
    tb.d[11] = { m1w1, m1p1, 33, 21, 336, 2, 0, 0, 0   };
    tb.d[12] = { m1w2, m1p2, 11, 16, 256, 0, 0, 0, 336 };
    pack_kernel<<<dim3(1386, 13), dim3(256), 0, stream>>>(tb);
    xbprep_kernel<<<128, 256, 0, stream>>>(xb, xcat, g, nrm);

    // layer 1 (F=6): fp32 kNN on xb; point-factored conv via pgemm1 + MODE 3
    knn_kernel<6><<<1024, 256, 0, stream>>>(xb, nrm, knn);
    pgemm1_kernel<<<5376, 256, 0, stream>>>(xb, c_w1[0], c_b1[0], Pp, Ppb);
    mfma_mlp<3><<<8192, 256, 0, stream>>>(nullptr, knn,
                                          nullptr, nullptr, w2p1, c_b2[0], Pp, Ppb,
                                          nullptr, xcat, 32, xfl, nrm);

    // layers 2..4: MFMA kNN + dual point-GEMM (Pa+b1, Pb) + factored conv.
    // Layer 4's xfl/nrm outputs are dead (m1 reads xcat only) -> nullptr.
    for (int l = 1; l < 4; ++l) {
        int dstslice = 32 + l * 256;
        bool last = (l == 3);
        knn_mfma<<<512, 256, 0, stream>>>(xfl, nrm, knn);
        pgemm_kernel<<<1024, 256, 0, stream>>>(xfl, w1a[l - 1], w1b[l - 1], c_b1[l], Pp, Ppb);
        mfma_mlp<3><<<8192, 256, 0, stream>>>(nullptr, knn,
                                              nullptr, nullptr, w2p[l - 1], c_b2[l], Pp, Ppb,
                                              nullptr, xcat, dstslice,
                                              last ? nullptr : xfl,
                                              last ? nullptr : nrm);
    }

    // m1 over Xcat with fused global_mean_pool -> g (zeroed in xbprep)
    mfma_mlp<2><<<1024, 256, 0, stream>>>(xcat, nullptr,
                                          m1p1, m1b1, m1p2, m1b2, nullptr, nullptr,
                                          g, nullptr, 0, nullptr, nullptr);

    head_kernel<<<64, 128, 0, stream>>>(g, m2w1, m2b1, m2w2, m2b2, (float*)d_out);
}